// Round 5
// baseline (115.637 us; speedup 1.0000x reference)
//
#include <hip/hip_runtime.h>
#include <math.h>
#include <stdint.h>

#define EMBED 512
#define HID 16
#define SEQ 1024

typedef unsigned short u16;
typedef __attribute__((ext_vector_type(8))) __bf16 bf16x8;
typedef __attribute__((ext_vector_type(4))) float f32x4;

__device__ __forceinline__ u16 f2bf(float f) {
    unsigned u = __float_as_uint(f);
    unsigned r = (u + 0x7FFFu + ((u >> 16) & 1u)) >> 16;   // RNE
    return (u16)r;
}
__device__ __forceinline__ float bf2f(u16 h) {
    return __uint_as_float(((unsigned)h) << 16);
}

// ---------------- Kernel 1: fold W1 into Wq/Wk ----------------
__global__ __launch_bounds__(256) void wc_kernel(
    const float* __restrict__ Wq, const float* __restrict__ Wk,
    const float* __restrict__ W1, float* __restrict__ WcT)
{
    __shared__ float w1s[EMBED];
    int h2 = blockIdx.x;              // 0..31
    int ab = h2 >> 4, h = h2 & 15;
    const float* Wmat = ab ? Wk : Wq;
    const float* w1row = W1 + (size_t)h * (2 * EMBED) + ab * EMBED;
    int t = threadIdx.x;
    for (int f = t; f < EMBED; f += 256) w1s[f] = w1row[f];
    __syncthreads();
    float acc0 = 0.f, acc1 = 0.f;
    int e0 = t, e1 = t + 256;
    for (int f = 0; f < EMBED; ++f) {
        float w = w1s[f];
        acc0 += w * Wmat[(size_t)f * EMBED + e0];
        acc1 += w * Wmat[(size_t)f * EMBED + e1];
    }
    WcT[(size_t)e0 * 32 + h2] = acc0;
    WcT[(size_t)e1 * 32 + h2] = acc1;
}

// ---------------- Kernel 2: A = x@Wc_a^T + b1, B = x@Wc_b^T ----------------
__global__ __launch_bounds__(256) void ab_kernel(
    const float* __restrict__ x, const float* __restrict__ WcT,
    const float* __restrict__ b1,
    float* __restrict__ A, float* __restrict__ Bm)
{
    __shared__ float xs[8][EMBED];
    __shared__ float wcs[EMBED * 32];
    int t = threadIdx.x;
    int s0 = blockIdx.x * 8;
    #pragma unroll
    for (int i = 0; i < 4; ++i) {
        int idx = t + i * 256;
        int row = idx >> 7, c4 = idx & 127;
        float4 vv = *(const float4*)(x + (size_t)(s0 + row) * EMBED + c4 * 4);
        *(float4*)&xs[row][c4 * 4] = vv;
    }
    #pragma unroll
    for (int i = 0; i < 16; ++i) {
        int idx = t + i * 256;
        ((float4*)wcs)[idx] = ((const float4*)WcT)[idx];
    }
    __syncthreads();
    int r = t >> 5, h2 = t & 31;
    const float* xr = xs[r];
    float acc = 0.f;
    #pragma unroll 8
    for (int k = 0; k < EMBED; ++k)
        acc += xr[k] * wcs[k * 32 + h2];
    int s = s0 + r;
    if (h2 < HID) A[(size_t)s * HID + h2] = acc + b1[h2];
    else          Bm[(size_t)s * HID + (h2 - 16)] = acc;
}

// ---------------- Kernel 3: split fp32 -> bf16 hi/lo ----------------
__global__ __launch_bounds__(256) void split_kernel(
    const float* __restrict__ in, u16* __restrict__ hi, u16* __restrict__ lo, int n4)
{
    int i = blockIdx.x * 256 + threadIdx.x;
    if (i >= n4) return;
    float4 v = ((const float4*)in)[i];
    u16 h0 = f2bf(v.x), h1 = f2bf(v.y), h2 = f2bf(v.z), h3 = f2bf(v.w);
    u16 l0 = f2bf(v.x - bf2f(h0)), l1 = f2bf(v.y - bf2f(h1));
    u16 l2 = f2bf(v.z - bf2f(h2)), l3 = f2bf(v.w - bf2f(h3));
    ((ushort4*)hi)[i] = make_ushort4(h0, h1, h2, h3);
    ((ushort4*)lo)[i] = make_ushort4(l0, l1, l2, l3);
}

// ---------------- MFMA GEMM: C[M][N] = A[M][K] * B[N][K]^T (split bf16) ----------------
// Block tile 128M x 64N, BK=64. 4 waves, wave-tile 64x32 (acc 4x2 of 16x16).
// LDS rows 128 B, XOR-swizzle slot = s ^ (row&7); linear LDS dest + pre-swizzled
// global source (rule 21).
template<int NR>
__device__ __forceinline__ void stageR(const u16* src, int ld, int kb0,
                                       u16* ldsb, int t)
{
    #pragma unroll
    for (int i = 0; i < NR / 32; ++i) {
        int row  = i * 32 + (t >> 3);
        int colb = (((t & 7) ^ ((t >> 3) & 7)) << 4);
        const char* g = (const char*)src + (size_t)row * ((size_t)ld * 2) + kb0 + colb;
        char* l = (char*)ldsb + i * 4096 + ((t >> 6) << 10);
        __builtin_amdgcn_global_load_lds(
            reinterpret_cast<const __attribute__((address_space(1))) unsigned int*>(
                reinterpret_cast<uintptr_t>(g)),
            reinterpret_cast<__attribute__((address_space(3))) unsigned int*>(
                reinterpret_cast<uintptr_t>(l)),
            16, 0, 0);
    }
}

__device__ __forceinline__ bf16x8 ldfrag(const u16* ldsb, int r, int s) {
    return *(const bf16x8*)((const char*)ldsb + r * 128 + (((s ^ (r & 7))) << 4));
}

// MODE 0: split-bf16 output (VT). MODE 1: fp32 atomic-add output (out).
// KSPLIT 2: blockIdx.y = (mtile<<1)|khalf. DBUF 1: 2-phase double buffer.
template<int MODE, int KSPLIT, int DBUF>
__global__ __launch_bounds__(256, 2) void mfma_gemm(
    const u16* __restrict__ Ah, const u16* __restrict__ Al, int lda,
    const u16* __restrict__ Bh, const u16* __restrict__ Bl, int ldb,
    int nkt, size_t batA, size_t batB,
    float* __restrict__ outF, u16* __restrict__ outH, u16* __restrict__ outL,
    int ldc)
{
    constexpr int AOFF = 128 * 64;          // u16 per A component (16 KB)
    constexpr int BOFF = 64 * 64;           // u16 per B component (8 KB)
    constexpr int BUFW = 2 * AOFF + 2 * BOFF;   // 24576 u16 = 48 KB
    __shared__ __attribute__((aligned(16))) u16 lds[(DBUF ? 2 : 1) * BUFW];
    int t = threadIdx.x;
    int l = t & 63, wid = t >> 6;
    int wm = (wid >> 1) * 64;               // 2 waves over M: 0,64
    int wn = (wid & 1) * 32;                // 2 waves over N: 0,32
    int m0, kt0;
    if (KSPLIT == 2) { m0 = (blockIdx.y >> 1) * 128; kt0 = (blockIdx.y & 1) * nkt; }
    else             { m0 = blockIdx.y * 128;        kt0 = 0; }
    int n0 = blockIdx.x * 64;
    size_t zb = blockIdx.z;
    const u16* pAh = Ah + zb * batA + (size_t)m0 * lda;
    const u16* pAl = Al + zb * batA + (size_t)m0 * lda;
    const u16* pBh = Bh + zb * batB + (size_t)n0 * ldb;
    const u16* pBl = Bl + zb * batB + (size_t)n0 * ldb;

    f32x4 acc[4][2] = {};

    auto STAGE = [&](int buf, int kt) {
        int kb0 = kt << 7;                  // 64 k * 2 B
        u16* base = lds + buf * BUFW;
        stageR<128>(pAh, lda, kb0, base,            t);
        stageR<128>(pAl, lda, kb0, base + AOFF,     t);
        stageR<64 >(pBh, ldb, kb0, base + 2 * AOFF, t);
        stageR<64 >(pBl, ldb, kb0, base + 2 * AOFF + BOFF, t);
    };
    auto COMPUTE = [&](int buf) {
        u16* lAh = lds + buf * BUFW;
        u16* lAl = lAh + AOFF;
        u16* lBh = lAh + 2 * AOFF;
        u16* lBl = lBh + BOFF;
        #pragma unroll
        for (int kk = 0; kk < 2; ++kk) {
            int sbase = (kk << 2) + (l >> 4);
            bf16x8 ah[4], al_[4], bh[2], bl_[2];
            #pragma unroll
            for (int mf = 0; mf < 4; ++mf) {
                int r = wm + mf * 16 + (l & 15);
                ah[mf]  = ldfrag(lAh, r, sbase);
                al_[mf] = ldfrag(lAl, r, sbase);
            }
            #pragma unroll
            for (int nf = 0; nf < 2; ++nf) {
                int r = wn + nf * 16 + (l & 15);
                bh[nf]  = ldfrag(lBh, r, sbase);
                bl_[nf] = ldfrag(lBl, r, sbase);
            }
            #pragma unroll
            for (int mf = 0; mf < 4; ++mf)
                #pragma unroll
                for (int nf = 0; nf < 2; ++nf) {
                    acc[mf][nf] = __builtin_amdgcn_mfma_f32_16x16x32_bf16(ah[mf],  bh[nf],  acc[mf][nf], 0, 0, 0);
                    acc[mf][nf] = __builtin_amdgcn_mfma_f32_16x16x32_bf16(ah[mf],  bl_[nf], acc[mf][nf], 0, 0, 0);
                    acc[mf][nf] = __builtin_amdgcn_mfma_f32_16x16x32_bf16(al_[mf], bh[nf],  acc[mf][nf], 0, 0, 0);
                }
        }
    };

    if (DBUF) {
        STAGE(0, kt0);
        __syncthreads();
        int cur = 0;
        for (int kt = kt0; kt + 1 < kt0 + nkt; ++kt) {
            STAGE(cur ^ 1, kt + 1);
            COMPUTE(cur);
            __syncthreads();
            cur ^= 1;
        }
        COMPUTE(cur);
    } else {
        for (int kt = kt0; kt < kt0 + nkt; ++kt) {
            STAGE(0, kt);
            __syncthreads();
            COMPUTE(0);
            __syncthreads();
        }
    }

    // epilogue: C row=(l>>4)*4+r (M-dim), col=l&15 (N-dim)  [m89-verified]
    int cr = (l >> 4) << 2;
    int cc = l & 15;
    #pragma unroll
    for (int mf = 0; mf < 4; ++mf)
        #pragma unroll
        for (int nf = 0; nf < 2; ++nf)
            #pragma unroll
            for (int r = 0; r < 4; ++r) {
                int row = m0 + wm + mf * 16 + cr + r;
                int col = n0 + wn + nf * 16 + cc;
                float v = acc[mf][nf][r];
                if (MODE == 0) {
                    u16 h = f2bf(v);
                    outH[(size_t)row * ldc + col] = h;
                    outL[(size_t)row * ldc + col] = f2bf(v - bf2f(h));
                } else {
                    unsafeAtomicAdd(&outF[zb * ((size_t)SEQ * EMBED) + (size_t)row * ldc + col], v);
                }
            }
}

// ---------------- Kernel: logits + softmax -> p (bf16 hi/lo, normalized) ----------------
// tanh(x) = 1 - 2/(exp2(K2*x)+1); pairwise-rcp fold; all state in NAMED registers
// (rule #20: no local arrays / pointer casts -> no scratch).
__global__ __launch_bounds__(256) void attn_kernel(
    const float* __restrict__ A, const float* __restrict__ Bm,
    const float* __restrict__ w2, u16* __restrict__ p_hi, u16* __restrict__ p_lo)
{
    const float K2 = 2.8853900817779268f;   // 2*log2(e)
    const float L2E = 1.4426950408889634f;  // log2(e)
    __shared__ float redm[4], reds[4];
    int blk = blockIdx.x;
    int b = blk >> 10, i = blk & 1023;
    int t = threadIdx.x;

    const float4* Ar = (const float4*)(A + (size_t)(b * SEQ + i) * HID);
    float4 a0 = Ar[0], a1 = Ar[1], a2 = Ar[2], a3 = Ar[3];
    float4 k0, k1, k2, k3;
    k0.x = K2 * a0.x; k0.y = K2 * a0.y; k0.z = K2 * a0.z; k0.w = K2 * a0.w;
    k1.x = K2 * a1.x; k1.y = K2 * a1.y; k1.z = K2 * a1.z; k1.w = K2 * a1.w;
    k2.x = K2 * a2.x; k2.y = K2 * a2.y; k2.z = K2 * a2.z; k2.w = K2 * a2.w;
    k3.x = K2 * a3.x; k3.y = K2 * a3.y; k3.z = K2 * a3.z; k3.w = K2 * a3.w;

    const float4* Wv = (const float4*)w2;
    float4 u0 = Wv[0], u1 = Wv[1], u2 = Wv[2], u3 = Wv[3];
    float Pa1 = -2.f*u0.x, Pa2 = -2.f*u0.y, Pas = Pa1 + Pa2;
    float Pb1 = -2.f*u0.z, Pb2 = -2.f*u0.w, Pbs = Pb1 + Pb2;
    float Pc1 = -2.f*u1.x, Pc2 = -2.f*u1.y, Pcs = Pc1 + Pc2;
    float Pd1 = -2.f*u1.z, Pd2 = -2.f*u1.w, Pds = Pd1 + Pd2;
    float Pe1 = -2.f*u2.x, Pe2 = -2.f*u2.y, Pes = Pe1 + Pe2;
    float Pf1 = -2.f*u2.z, Pf2 = -2.f*u2.w, Pfs = Pf1 + Pf2;
    float Pg1 = -2.f*u3.x, Pg2 = -2.f*u3.y, Pgs = Pg1 + Pg2;
    float Ph1 = -2.f*u3.z, Ph2 = -2.f*u3.w, Phs = Ph1 + Ph2;

    const float* Bb = Bm + (size_t)b * SEQ * HID;
    const float4* B0 = (const float4*)(Bb + (size_t)(t      ) * HID);
    const float4* B1 = (const float4*)(Bb + (size_t)(t + 256) * HID);
    const float4* B2 = (const float4*)(Bb + (size_t)(t + 512) * HID);
    const float4* B3 = (const float4*)(Bb + (size_t)(t + 768) * HID);
    float4 c00 = B0[0], c01 = B0[1], c02 = B0[2], c03 = B0[3];
    float4 c10 = B1[0], c11 = B1[1], c12 = B1[2], c13 = B1[3];
    float4 c20 = B2[0], c21 = B2[1], c22 = B2[2], c23 = B2[3];
    float4 c30 = B3[0], c31 = B3[1], c32 = B3[2], c33 = B3[3];

#define PAIRF(bx, by, kx, ky, P1, P2, PS) { \
    float e1 = __builtin_amdgcn_exp2f(fmaf(K2, (bx), (kx))); \
    float e2 = __builtin_amdgcn_exp2f(fmaf(K2, (by), (ky))); \
    float dd = fmaf(e1, e2, e1) + e2 + 1.0f; \
    float nn = fmaf((P1), e2, (PS)); nn = fmaf((P2), e1, nn); \
    s = fmaf(nn, __builtin_amdgcn_rcpf(dd), s); }

#define ROWL(LG, v0, v1, v2, v3) { float s = 0.f; \
    PAIRF(v0.x, v0.y, k0.x, k0.y, Pa1, Pa2, Pas) \
    PAIRF(v0.z, v0.w, k0.z, k0.w, Pb1, Pb2, Pbs) \
    PAIRF(v1.x, v1.y, k1.x, k1.y, Pc1, Pc2, Pcs) \
    PAIRF(v1.z, v1.w, k1.z, k1.w, Pd1, Pd2, Pds) \
    PAIRF(v2.x, v2.y, k2.x, k2.y, Pe1, Pe2, Pes) \
    PAIRF(v2.z, v2.w, k2.z, k2.w, Pf1, Pf2, Pfs) \
    PAIRF(v3.x, v3.y, k3.x, k3.y, Pg1, Pg2, Pgs) \
    PAIRF(v3.z, v3.w, k3.z, k3.w, Ph1, Ph2, Phs) \
    LG = s; }

    float lg0, lg1, lg2, lg3;
    ROWL(lg0, c00, c01, c02, c03)
    ROWL(lg1, c10, c11, c12, c13)
    ROWL(lg2, c20, c21, c22, c23)
    ROWL(lg3, c30, c31, c32, c33)
#undef ROWL
#undef PAIRF

    float m = fmaxf(fmaxf(lg0, lg1), fmaxf(lg2, lg3));
    #pragma unroll
    for (int o = 32; o > 0; o >>= 1) m = fmaxf(m, __shfl_xor(m, o));
    if ((t & 63) == 0) redm[t >> 6] = m;
    __syncthreads();
    m = fmaxf(fmaxf(redm[0], redm[1]), fmaxf(redm[2], redm[3]));
    float p0 = __builtin_amdgcn_exp2f((lg0 - m) * L2E);
    float p1 = __builtin_amdgcn_exp2f((lg1 - m) * L2E);
    float p2 = __builtin_amdgcn_exp2f((lg2 - m) * L2E);
    float p3 = __builtin_amdgcn_exp2f((lg3 - m) * L2E);
    float sum = (p0 + p1) + (p2 + p3);
    #pragma unroll
    for (int o = 32; o > 0; o >>= 1) sum += __shfl_xor(sum, o);
    if ((t & 63) == 0) reds[t >> 6] = sum;
    __syncthreads();
    sum = reds[0] + reds[1] + reds[2] + reds[3];
    float inv = __fdividef(1.0f, sum);
    size_t base = (size_t)(b * SEQ + i) * SEQ;
    p0 *= inv; p1 *= inv; p2 *= inv; p3 *= inv;
    u16 h0 = f2bf(p0), h1 = f2bf(p1), h2 = f2bf(p2), h3 = f2bf(p3);
    p_hi[base + t      ] = h0;  p_lo[base + t      ] = f2bf(p0 - bf2f(h0));
    p_hi[base + t + 256] = h1;  p_lo[base + t + 256] = f2bf(p1 - bf2f(h1));
    p_hi[base + t + 512] = h2;  p_lo[base + t + 512] = f2bf(p2 - bf2f(h2));
    p_hi[base + t + 768] = h3;  p_lo[base + t + 768] = f2bf(p3 - bf2f(h3));
}

extern "C" void kernel_launch(void* const* d_in, const int* in_sizes, int n_in,
                              void* d_out, int out_size, void* d_ws, size_t ws_size,
                              hipStream_t stream) {
    const float* x  = (const float*)d_in[0];
    const float* Wq = (const float*)d_in[1];
    const float* Wk = (const float*)d_in[2];
    const float* Wv = (const float*)d_in[3];
    const float* W1 = (const float*)d_in[4];
    const float* b1 = (const float*)d_in[5];
    const float* w2 = (const float*)d_in[6];
    // d_in[7] = b2: softmax shift-invariant, unused.

    char* ws = (char*)d_ws;
    float* WcT   = (float*)(ws + 0);          //    65,536 B
    float* A     = (float*)(ws + 65536);      //   262,144 B
    float* Bm    = (float*)(ws + 327680);     //   262,144 B
    u16*   VT_hi = (u16*)(ws + 589824);       // 4,194,304 B (512 x 4096)
    u16*   VT_lo = (u16*)(ws + 4784128);      // 4,194,304 B
    u16*   Xreg  = (u16*)(ws + 8978432);      // 8,388,608 B: x_hi|x_lo, later p_lo
    u16*   Preg  = (u16*)(ws + 17367040);     // 8,388,608 B: wv_hi|wv_lo, later p_hi
    u16* x_hi  = Xreg;
    u16* x_lo  = Xreg + 2097152;
    u16* p_lo  = Xreg;
    u16* wv_hi = Preg;
    u16* wv_lo = Preg + 262144;
    u16* p_hi  = Preg;
    float* out = (float*)d_out;

    hipLaunchKernelGGL(wc_kernel, dim3(32), dim3(256), 0, stream, Wq, Wk, W1, WcT);
    hipLaunchKernelGGL(ab_kernel, dim3(512), dim3(256), 0, stream, x, WcT, b1, A, Bm);
    hipLaunchKernelGGL(split_kernel, dim3(2048), dim3(256), 0, stream, x, x_hi, x_lo, 524288);
    hipLaunchKernelGGL(split_kernel, dim3(256), dim3(256), 0, stream, Wv, wv_hi, wv_lo, 65536);
    // VT[512][4096] = Wv(rows) x x(rows)^T  (M=512, N=4096, K=512) — dbuf, no split
    hipLaunchKernelGGL((mfma_gemm<0, 1, 1>), dim3(64, 4, 1), dim3(256), 0, stream,
                       wv_hi, wv_lo, EMBED, x_hi, x_lo, EMBED,
                       8, (size_t)0, (size_t)0, (float*)nullptr, VT_hi, VT_lo, 4096);
    // p (overwrites wv/x regions — stream-ordered after vgemm)
    hipLaunchKernelGGL(attn_kernel, dim3(4096), dim3(256), 0, stream, A, Bm, w2, p_hi, p_lo);
    // out[b*1024+m][n] = sum_k p[b][m][k] * VT[n][b*1024+k]  (split-K=2, atomic)
    hipMemsetAsync(d_out, 0, (size_t)out_size * sizeof(float), stream);
    hipLaunchKernelGGL((mfma_gemm<1, 2, 0>), dim3(8, 16, 4), dim3(256), 0, stream,
                       p_hi, p_lo, SEQ, VT_hi, VT_lo, 4096,
                       8, (size_t)SEQ * SEQ, (size_t)SEQ, out, (u16*)nullptr, (u16*)nullptr, EMBED);
}

// Round 6
// 110.891 us; speedup vs baseline: 1.0428x; 1.0428x over previous
//
#include <hip/hip_runtime.h>
#include <math.h>
#include <stdint.h>

#define EMBED 512
#define HID 16
#define SEQ 1024

typedef unsigned short u16;
typedef __attribute__((ext_vector_type(8))) __bf16 bf16x8;
typedef __attribute__((ext_vector_type(4))) float f32x4;

__device__ __forceinline__ u16 f2bf(float f) {
    unsigned u = __float_as_uint(f);
    unsigned r = (u + 0x7FFFu + ((u >> 16) & 1u)) >> 16;   // RNE
    return (u16)r;
}
__device__ __forceinline__ float bf2f(u16 h) {
    return __uint_as_float(((unsigned)h) << 16);
}

// ---------------- Kernel 1: fold W1 into Wq/Wk  (+fused Wv hi/lo split) ----------------
// blocks 0..31: WcT; blocks 32..287: Wv split.
__global__ __launch_bounds__(256) void wc_kernel(
    const float* __restrict__ Wq, const float* __restrict__ Wk,
    const float* __restrict__ W1, const float* __restrict__ Wvm,
    float* __restrict__ WcT, u16* __restrict__ wv_hi, u16* __restrict__ wv_lo)
{
    __shared__ float w1s[EMBED];
    int t = threadIdx.x;
    if (blockIdx.x >= 32) {
        int i = (blockIdx.x - 32) * 256 + t;       // float4 idx < 65536
        float4 v = ((const float4*)Wvm)[i];
        u16 h0 = f2bf(v.x), h1 = f2bf(v.y), h2 = f2bf(v.z), h3 = f2bf(v.w);
        ((ushort4*)wv_hi)[i] = make_ushort4(h0, h1, h2, h3);
        ((ushort4*)wv_lo)[i] = make_ushort4(f2bf(v.x - bf2f(h0)), f2bf(v.y - bf2f(h1)),
                                            f2bf(v.z - bf2f(h2)), f2bf(v.w - bf2f(h3)));
        return;
    }
    int h2 = blockIdx.x;              // 0..31
    int ab = h2 >> 4, h = h2 & 15;
    const float* Wmat = ab ? Wk : Wq;
    const float* w1row = W1 + (size_t)h * (2 * EMBED) + ab * EMBED;
    for (int f = t; f < EMBED; f += 256) w1s[f] = w1row[f];
    __syncthreads();
    float acc0 = 0.f, acc1 = 0.f;
    int e0 = t, e1 = t + 256;
    for (int f = 0; f < EMBED; ++f) {
        float w = w1s[f];
        acc0 += w * Wmat[(size_t)f * EMBED + e0];
        acc1 += w * Wmat[(size_t)f * EMBED + e1];
    }
    WcT[(size_t)e0 * 32 + h2] = acc0;
    WcT[(size_t)e1 * 32 + h2] = acc1;
}

// ---------------- Kernel 2: A/Bm projections (+fused x hi/lo split) ----------------
__global__ __launch_bounds__(256) void ab_kernel(
    const float* __restrict__ x, const float* __restrict__ WcT,
    const float* __restrict__ b1,
    float* __restrict__ A, float* __restrict__ Bm,
    u16* __restrict__ x_hi, u16* __restrict__ x_lo)
{
    __shared__ float xs[8][EMBED];
    __shared__ float wcs[EMBED * 32];
    int t = threadIdx.x;
    int s0 = blockIdx.x * 8;
    #pragma unroll
    for (int i = 0; i < 4; ++i) {
        int idx = t + i * 256;
        int row = idx >> 7, c4 = idx & 127;
        float4 vv = *(const float4*)(x + (size_t)(s0 + row) * EMBED + c4 * 4);
        *(float4*)&xs[row][c4 * 4] = vv;
    }
    #pragma unroll
    for (int i = 0; i < 16; ++i) {
        int idx = t + i * 256;
        ((float4*)wcs)[idx] = ((const float4*)WcT)[idx];
    }
    __syncthreads();
    // fused x split (reads LDS, writes bf16 hi/lo)
    #pragma unroll
    for (int i = 0; i < 4; ++i) {
        int idx = t + i * 256;
        int row = idx >> 7, c4 = idx & 127;
        float4 v = *(const float4*)&xs[row][c4 * 4];
        u16 h0 = f2bf(v.x), h1 = f2bf(v.y), h2 = f2bf(v.z), h3 = f2bf(v.w);
        int gi = (s0 + row) * 128 + c4;            // ushort4 index
        ((ushort4*)x_hi)[gi] = make_ushort4(h0, h1, h2, h3);
        ((ushort4*)x_lo)[gi] = make_ushort4(f2bf(v.x - bf2f(h0)), f2bf(v.y - bf2f(h1)),
                                            f2bf(v.z - bf2f(h2)), f2bf(v.w - bf2f(h3)));
    }
    int r = t >> 5, h2 = t & 31;
    const float* xr = xs[r];
    float acc = 0.f;
    #pragma unroll 8
    for (int k = 0; k < EMBED; ++k)
        acc += xr[k] * wcs[k * 32 + h2];
    int s = s0 + r;
    if (h2 < HID) A[(size_t)s * HID + h2] = acc + b1[h2];
    else          Bm[(size_t)s * HID + (h2 - 16)] = acc;
}

// ---------------- MFMA GEMM: C[M][N] = A[M][K]*B[N][K]^T (split bf16, 3-term) ----------
// Tile BM x BN (BM=AM*32, BN=AN*32), BK=64. 4 waves as 2x2; wave-tile (AM*16)x(AN*16).
// LDS rows 128 B, XOR-swizzle slot = s ^ (row&7); linear LDS dest + pre-swizzled
// global source (rule 21).
template<int NR>
__device__ __forceinline__ void stageR(const u16* src, int ld, int kt,
                                       u16* ldsb, int t)
{
    int kb0 = kt << 7;
    #pragma unroll
    for (int i = 0; i < NR / 32; ++i) {
        int row  = i * 32 + (t >> 3);
        int colb = (((t & 7) ^ ((t >> 3) & 7)) << 4);
        const char* g = (const char*)src + (size_t)row * ((size_t)ld * 2) + kb0 + colb;
        char* l = (char*)ldsb + i * 4096 + ((t >> 6) << 10);
        __builtin_amdgcn_global_load_lds(
            reinterpret_cast<const __attribute__((address_space(1))) unsigned int*>(
                reinterpret_cast<uintptr_t>(g)),
            reinterpret_cast<__attribute__((address_space(3))) unsigned int*>(
                reinterpret_cast<uintptr_t>(l)),
            16, 0, 0);
    }
}

__device__ __forceinline__ bf16x8 ldfrag(const u16* ldsb, int r, int s) {
    return *(const bf16x8*)((const char*)ldsb + r * 128 + (((s ^ (r & 7))) << 4));
}

// MODE 0: split-bf16 output (VT). MODE 2: fp32 partial slab (split-K).
template<int MODE, int AM, int AN, int KSPLIT, int DBUF>
__global__ __launch_bounds__(256, DBUF ? 1 : 3) void mfma_gemm(
    const u16* __restrict__ Ah, const u16* __restrict__ Al, int lda,
    const u16* __restrict__ Bh, const u16* __restrict__ Bl, int ldb,
    int nkt, size_t batA, size_t batB,
    float* __restrict__ outF, u16* __restrict__ outH, u16* __restrict__ outL,
    int ldc)
{
    constexpr int BM = AM * 32, BN = AN * 32;
    constexpr int AOFF = BM * 64;               // u16
    constexpr int BOFF = BN * 64;               // u16
    constexpr int BUFW = 2 * (AOFF + BOFF);
    __shared__ __attribute__((aligned(16))) u16 lds[(DBUF ? 2 : 1) * BUFW];
    int t = threadIdx.x;
    int l = t & 63, wid = t >> 6;
    int wm = (wid >> 1) * (AM * 16);
    int wn = (wid & 1) * (AN * 16);
    int m0 = blockIdx.y * BM;
    int n0 = blockIdx.x * BN;
    int zb = blockIdx.z / KSPLIT;
    int kc = blockIdx.z % KSPLIT;
    int kt0 = kc * nkt;
    const u16* pAh = Ah + (size_t)zb * batA + (size_t)m0 * lda;
    const u16* pAl = Al + (size_t)zb * batA + (size_t)m0 * lda;
    const u16* pBh = Bh + (size_t)zb * batB + (size_t)n0 * ldb;
    const u16* pBl = Bl + (size_t)zb * batB + (size_t)n0 * ldb;

    f32x4 acc[AM][AN] = {};

    auto STAGE = [&](int buf, int kt) {
        u16* base = lds + buf * BUFW;
        stageR<BM>(pAh, lda, kt, base,            t);
        stageR<BM>(pAl, lda, kt, base + AOFF,     t);
        stageR<BN>(pBh, ldb, kt, base + 2 * AOFF, t);
        stageR<BN>(pBl, ldb, kt, base + 2 * AOFF + BOFF, t);
    };
    auto COMPUTE = [&](int buf) {
        u16* lAh = lds + buf * BUFW;
        u16* lAl = lAh + AOFF;
        u16* lBh = lAh + 2 * AOFF;
        u16* lBl = lBh + BOFF;
        #pragma unroll
        for (int kk = 0; kk < 2; ++kk) {
            int sbase = (kk << 2) + (l >> 4);
            bf16x8 ah[AM], al_[AM], bh[AN], bl_[AN];
            #pragma unroll
            for (int mf = 0; mf < AM; ++mf) {
                int r = wm + mf * 16 + (l & 15);
                ah[mf]  = ldfrag(lAh, r, sbase);
                al_[mf] = ldfrag(lAl, r, sbase);
            }
            #pragma unroll
            for (int nf = 0; nf < AN; ++nf) {
                int r = wn + nf * 16 + (l & 15);
                bh[nf]  = ldfrag(lBh, r, sbase);
                bl_[nf] = ldfrag(lBl, r, sbase);
            }
            #pragma unroll
            for (int mf = 0; mf < AM; ++mf)
                #pragma unroll
                for (int nf = 0; nf < AN; ++nf) {
                    acc[mf][nf] = __builtin_amdgcn_mfma_f32_16x16x32_bf16(ah[mf],  bh[nf],  acc[mf][nf], 0, 0, 0);
                    acc[mf][nf] = __builtin_amdgcn_mfma_f32_16x16x32_bf16(ah[mf],  bl_[nf], acc[mf][nf], 0, 0, 0);
                    acc[mf][nf] = __builtin_amdgcn_mfma_f32_16x16x32_bf16(al_[mf], bh[nf],  acc[mf][nf], 0, 0, 0);
                }
        }
    };

    if (DBUF) {
        STAGE(0, kt0);
        __syncthreads();
        int cur = 0;
        for (int kt = kt0; kt + 1 < kt0 + nkt; ++kt) {
            STAGE(cur ^ 1, kt + 1);
            COMPUTE(cur);
            __syncthreads();
            cur ^= 1;
        }
        COMPUTE(cur);
    } else {
        for (int kt = kt0; kt < kt0 + nkt; ++kt) {
            STAGE(0, kt);
            __syncthreads();
            COMPUTE(0);
            __syncthreads();
        }
    }

    // epilogue: C row=(l>>4)*4+r (M-dim), col=l&15 (N-dim)  [m89-verified]
    int cr = (l >> 4) << 2;
    int cc = l & 15;
    #pragma unroll
    for (int mf = 0; mf < AM; ++mf)
        #pragma unroll
        for (int nf = 0; nf < AN; ++nf)
            #pragma unroll
            for (int r = 0; r < 4; ++r) {
                int row = m0 + wm + mf * 16 + cr + r;
                int col = n0 + wn + nf * 16 + cc;
                float v = acc[mf][nf][r];
                if (MODE == 0) {
                    u16 h = f2bf(v);
                    outH[(size_t)row * ldc + col] = h;
                    outL[(size_t)row * ldc + col] = f2bf(v - bf2f(h));
                } else {
                    // partial slab kc: [4096 x 512] fp32
                    outF[(size_t)kc * ((size_t)4 * SEQ * EMBED)
                         + ((size_t)(zb * SEQ + row) * ldc + col)] = v;
                }
            }
}

// ---------------- Kernel: split-K reduce: out = sum of 4 partial slabs ----------------
__global__ __launch_bounds__(256) void reduce_kernel(
    const float* __restrict__ part, float* __restrict__ out)
{
    const size_t SLAB4 = (size_t)4 * SEQ * EMBED / 4;   // float4 per slab
    size_t i = (size_t)blockIdx.x * 256 + threadIdx.x;  // < 524288
    float4 a = ((const float4*)part)[i];
    float4 b = ((const float4*)part)[i + SLAB4];
    float4 c = ((const float4*)part)[i + 2 * SLAB4];
    float4 d = ((const float4*)part)[i + 3 * SLAB4];
    float4 o = make_float4((a.x + b.x) + (c.x + d.x), (a.y + b.y) + (c.y + d.y),
                           (a.z + b.z) + (c.z + d.z), (a.w + b.w) + (c.w + d.w));
    ((float4*)out)[i] = o;
}

// ---------------- Kernel: logits + softmax -> p (bf16 hi/lo, normalized) ----------------
// tanh(x) = 1 - 2/(exp2(K2*x)+1); pairwise-rcp fold; all state in NAMED registers
// (rule #20: no local arrays / pointer casts -> no scratch).
__global__ __launch_bounds__(256) void attn_kernel(
    const float* __restrict__ A, const float* __restrict__ Bm,
    const float* __restrict__ w2, u16* __restrict__ p_hi, u16* __restrict__ p_lo)
{
    const float K2 = 2.8853900817779268f;   // 2*log2(e)
    const float L2E = 1.4426950408889634f;  // log2(e)
    __shared__ float redm[4], reds[4];
    int blk = blockIdx.x;
    int b = blk >> 10, i = blk & 1023;
    int t = threadIdx.x;

    const float4* Ar = (const float4*)(A + (size_t)(b * SEQ + i) * HID);
    float4 a0 = Ar[0], a1 = Ar[1], a2 = Ar[2], a3 = Ar[3];
    float4 k0, k1, k2, k3;
    k0.x = K2 * a0.x; k0.y = K2 * a0.y; k0.z = K2 * a0.z; k0.w = K2 * a0.w;
    k1.x = K2 * a1.x; k1.y = K2 * a1.y; k1.z = K2 * a1.z; k1.w = K2 * a1.w;
    k2.x = K2 * a2.x; k2.y = K2 * a2.y; k2.z = K2 * a2.z; k2.w = K2 * a2.w;
    k3.x = K2 * a3.x; k3.y = K2 * a3.y; k3.z = K2 * a3.z; k3.w = K2 * a3.w;

    const float4* Wv = (const float4*)w2;
    float4 u0 = Wv[0], u1 = Wv[1], u2 = Wv[2], u3 = Wv[3];
    float Pa1 = -2.f*u0.x, Pa2 = -2.f*u0.y, Pas = Pa1 + Pa2;
    float Pb1 = -2.f*u0.z, Pb2 = -2.f*u0.w, Pbs = Pb1 + Pb2;
    float Pc1 = -2.f*u1.x, Pc2 = -2.f*u1.y, Pcs = Pc1 + Pc2;
    float Pd1 = -2.f*u1.z, Pd2 = -2.f*u1.w, Pds = Pd1 + Pd2;
    float Pe1 = -2.f*u2.x, Pe2 = -2.f*u2.y, Pes = Pe1 + Pe2;
    float Pf1 = -2.f*u2.z, Pf2 = -2.f*u2.w, Pfs = Pf1 + Pf2;
    float Pg1 = -2.f*u3.x, Pg2 = -2.f*u3.y, Pgs = Pg1 + Pg2;
    float Ph1 = -2.f*u3.z, Ph2 = -2.f*u3.w, Phs = Ph1 + Ph2;

    const float* Bb = Bm + (size_t)b * SEQ * HID;
    const float4* B0 = (const float4*)(Bb + (size_t)(t      ) * HID);
    const float4* B1 = (const float4*)(Bb + (size_t)(t + 256) * HID);
    const float4* B2 = (const float4*)(Bb + (size_t)(t + 512) * HID);
    const float4* B3 = (const float4*)(Bb + (size_t)(t + 768) * HID);
    float4 c00 = B0[0], c01 = B0[1], c02 = B0[2], c03 = B0[3];
    float4 c10 = B1[0], c11 = B1[1], c12 = B1[2], c13 = B1[3];
    float4 c20 = B2[0], c21 = B2[1], c22 = B2[2], c23 = B2[3];
    float4 c30 = B3[0], c31 = B3[1], c32 = B3[2], c33 = B3[3];

#define PAIRF(bx, by, kx, ky, P1, P2, PS) { \
    float e1 = __builtin_amdgcn_exp2f(fmaf(K2, (bx), (kx))); \
    float e2 = __builtin_amdgcn_exp2f(fmaf(K2, (by), (ky))); \
    float dd = fmaf(e1, e2, e1) + e2 + 1.0f; \
    float nn = fmaf((P1), e2, (PS)); nn = fmaf((P2), e1, nn); \
    s = fmaf(nn, __builtin_amdgcn_rcpf(dd), s); }

#define ROWL(LG, v0, v1, v2, v3) { float s = 0.f; \
    PAIRF(v0.x, v0.y, k0.x, k0.y, Pa1, Pa2, Pas) \
    PAIRF(v0.z, v0.w, k0.z, k0.w, Pb1, Pb2, Pbs) \
    PAIRF(v1.x, v1.y, k1.x, k1.y, Pc1, Pc2, Pcs) \
    PAIRF(v1.z, v1.w, k1.z, k1.w, Pd1, Pd2, Pds) \
    PAIRF(v2.x, v2.y, k2.x, k2.y, Pe1, Pe2, Pes) \
    PAIRF(v2.z, v2.w, k2.z, k2.w, Pf1, Pf2, Pfs) \
    PAIRF(v3.x, v3.y, k3.x, k3.y, Pg1, Pg2, Pgs) \
    PAIRF(v3.z, v3.w, k3.z, k3.w, Ph1, Ph2, Phs) \
    LG = s; }

    float lg0, lg1, lg2, lg3;
    ROWL(lg0, c00, c01, c02, c03)
    ROWL(lg1, c10, c11, c12, c13)
    ROWL(lg2, c20, c21, c22, c23)
    ROWL(lg3, c30, c31, c32, c33)
#undef ROWL
#undef PAIRF

    float m = fmaxf(fmaxf(lg0, lg1), fmaxf(lg2, lg3));
    #pragma unroll
    for (int o = 32; o > 0; o >>= 1) m = fmaxf(m, __shfl_xor(m, o));
    if ((t & 63) == 0) redm[t >> 6] = m;
    __syncthreads();
    m = fmaxf(fmaxf(redm[0], redm[1]), fmaxf(redm[2], redm[3]));
    float p0 = __builtin_amdgcn_exp2f((lg0 - m) * L2E);
    float p1 = __builtin_amdgcn_exp2f((lg1 - m) * L2E);
    float p2 = __builtin_amdgcn_exp2f((lg2 - m) * L2E);
    float p3 = __builtin_amdgcn_exp2f((lg3 - m) * L2E);
    float sum = (p0 + p1) + (p2 + p3);
    #pragma unroll
    for (int o = 32; o > 0; o >>= 1) sum += __shfl_xor(sum, o);
    if ((t & 63) == 0) reds[t >> 6] = sum;
    __syncthreads();
    sum = reds[0] + reds[1] + reds[2] + reds[3];
    float inv = __fdividef(1.0f, sum);
    size_t base = (size_t)(b * SEQ + i) * SEQ;
    p0 *= inv; p1 *= inv; p2 *= inv; p3 *= inv;
    u16 h0 = f2bf(p0), h1 = f2bf(p1), h2 = f2bf(p2), h3 = f2bf(p3);
    p_hi[base + t      ] = h0;  p_lo[base + t      ] = f2bf(p0 - bf2f(h0));
    p_hi[base + t + 256] = h1;  p_lo[base + t + 256] = f2bf(p1 - bf2f(h1));
    p_hi[base + t + 512] = h2;  p_lo[base + t + 512] = f2bf(p2 - bf2f(h2));
    p_hi[base + t + 768] = h3;  p_lo[base + t + 768] = f2bf(p3 - bf2f(h3));
}

extern "C" void kernel_launch(void* const* d_in, const int* in_sizes, int n_in,
                              void* d_out, int out_size, void* d_ws, size_t ws_size,
                              hipStream_t stream) {
    const float* x   = (const float*)d_in[0];
    const float* Wq  = (const float*)d_in[1];
    const float* Wk  = (const float*)d_in[2];
    const float* Wvm = (const float*)d_in[3];
    const float* W1  = (const float*)d_in[4];
    const float* b1  = (const float*)d_in[5];
    const float* w2  = (const float*)d_in[6];
    // d_in[7] = b2: softmax shift-invariant, unused.

    char* ws = (char*)d_ws;
    float* WcT   = (float*)(ws + 0);          //    65,536 B
    float* A     = (float*)(ws + 65536);      //   262,144 B
    float* Bm    = (float*)(ws + 327680);     //   262,144 B
    u16*   VT_hi = (u16*)(ws + 589824);       // 4,194,304 B (512 x 4096)
    u16*   VT_lo = (u16*)(ws + 4784128);      // 4,194,304 B
    u16*   Xreg  = (u16*)(ws + 8978432);      // 8,388,608 B: x_hi|x_lo, later p_lo
    u16*   Preg  = (u16*)(ws + 17367040);     // 8,388,608 B: wv_hi|wv_lo, later p_hi
    float* Pp    = (float*)(ws + 25755648);   // 33,554,432 B: 4 partial slabs
    u16* x_hi  = Xreg;
    u16* x_lo  = Xreg + 2097152;
    u16* p_lo  = Xreg;
    u16* wv_hi = Preg;
    u16* wv_lo = Preg + 262144;
    u16* p_hi  = Preg;
    float* out = (float*)d_out;

    // 1. weight-fold + Wv split
    hipLaunchKernelGGL(wc_kernel, dim3(288), dim3(256), 0, stream,
                       Wq, Wk, W1, Wvm, WcT, wv_hi, wv_lo);
    // 2. A/Bm + x split
    hipLaunchKernelGGL(ab_kernel, dim3(512), dim3(256), 0, stream,
                       x, WcT, b1, A, Bm, x_hi, x_lo);
    // 3. VT[512][4096] = Wv x x^T  (M=512, N=4096, K=512): 64x128 tile, dbuf
    hipLaunchKernelGGL((mfma_gemm<0, 2, 4, 1, 1>), dim3(32, 8, 1), dim3(256), 0, stream,
                       wv_hi, wv_lo, EMBED, x_hi, x_lo, EMBED,
                       8, (size_t)0, (size_t)0, (float*)nullptr, VT_hi, VT_lo, 4096);
    // 4. logits + softmax (overwrites wv/x regions — stream-ordered after vgemm)
    hipLaunchKernelGGL(attn_kernel, dim3(4096), dim3(256), 0, stream, A, Bm, w2, p_hi, p_lo);
    // 5. partial[kc] = p[:, kc-chunk] @ VT[:, kc-chunk]^T : 128x64 tile, split-K=4
    hipLaunchKernelGGL((mfma_gemm<2, 4, 2, 4, 0>), dim3(8, 8, 16), dim3(256), 0, stream,
                       p_hi, p_lo, SEQ, VT_hi, VT_lo, 4096,
                       4, (size_t)SEQ * SEQ, (size_t)SEQ, Pp, (u16*)nullptr, (u16*)nullptr, EMBED);
    // 6. out = sum of 4 slabs (deterministic order)
    hipLaunchKernelGGL(reduce_kernel, dim3(2048), dim3(256), 0, stream, Pp, out);
}

// Round 7
// 87.243 us; speedup vs baseline: 1.3255x; 1.2711x over previous
//
#include <hip/hip_runtime.h>
#include <math.h>
#include <stdint.h>

#define EMBED 512
#define HID 16
#define SEQ 1024

typedef unsigned short u16;
typedef __attribute__((ext_vector_type(8))) __bf16 bf16x8;
typedef __attribute__((ext_vector_type(4))) float f32x4;

__device__ __forceinline__ u16 f2bf(float f) {
    unsigned u = __float_as_uint(f);
    unsigned r = (u + 0x7FFFu + ((u >> 16) & 1u)) >> 16;   // RNE
    return (u16)r;
}
__device__ __forceinline__ float bf2f(u16 h) {
    return __uint_as_float(((unsigned)h) << 16);
}
__device__ __forceinline__ void gload16(const void* g, void* d) {
    __builtin_amdgcn_global_load_lds(
        reinterpret_cast<const __attribute__((address_space(1))) unsigned int*>(
            reinterpret_cast<uintptr_t>(g)),
        reinterpret_cast<__attribute__((address_space(3))) unsigned int*>(
            reinterpret_cast<uintptr_t>(d)),
        16, 0, 0);
}

// ---------------- Kernel 1: fold W1 into Wq/Wk (+fused Wv hi/lo split) ----------------
__global__ __launch_bounds__(256) void wc_kernel(
    const float* __restrict__ Wq, const float* __restrict__ Wk,
    const float* __restrict__ W1, const float* __restrict__ Wvm,
    float* __restrict__ WcT, u16* __restrict__ wv_hi, u16* __restrict__ wv_lo)
{
    __shared__ float w1s[EMBED];
    int t = threadIdx.x;
    if (blockIdx.x >= 32) {
        int i = (blockIdx.x - 32) * 256 + t;       // float4 idx < 65536
        float4 v = ((const float4*)Wvm)[i];
        u16 h0 = f2bf(v.x), h1 = f2bf(v.y), h2 = f2bf(v.z), h3 = f2bf(v.w);
        ((ushort4*)wv_hi)[i] = make_ushort4(h0, h1, h2, h3);
        ((ushort4*)wv_lo)[i] = make_ushort4(f2bf(v.x - bf2f(h0)), f2bf(v.y - bf2f(h1)),
                                            f2bf(v.z - bf2f(h2)), f2bf(v.w - bf2f(h3)));
        return;
    }
    int h2 = blockIdx.x;              // 0..31
    int ab = h2 >> 4, h = h2 & 15;
    const float* Wmat = ab ? Wk : Wq;
    const float* w1row = W1 + (size_t)h * (2 * EMBED) + ab * EMBED;
    for (int f = t; f < EMBED; f += 256) w1s[f] = w1row[f];
    __syncthreads();
    float acc0 = 0.f, acc1 = 0.f;
    int e0 = t, e1 = t + 256;
    for (int f = 0; f < EMBED; ++f) {
        float w = w1s[f];
        acc0 += w * Wmat[(size_t)f * EMBED + e0];
        acc1 += w * Wmat[(size_t)f * EMBED + e1];
    }
    WcT[(size_t)e0 * 32 + h2] = acc0;
    WcT[(size_t)e1 * 32 + h2] = acc1;
}

// ---------------- Kernel 2: A/Bm projections (+fused x_hi split) ----------------
__global__ __launch_bounds__(256) void ab_kernel(
    const float* __restrict__ x, const float* __restrict__ WcT,
    const float* __restrict__ b1,
    float* __restrict__ A, float* __restrict__ Bm, u16* __restrict__ x_hi)
{
    __shared__ float xs[8][EMBED];
    __shared__ float wcs[EMBED * 32];
    int t = threadIdx.x;
    int s0 = blockIdx.x * 8;
    #pragma unroll
    for (int i = 0; i < 4; ++i) {
        int idx = t + i * 256;
        int row = idx >> 7, c4 = idx & 127;
        float4 vv = *(const float4*)(x + (size_t)(s0 + row) * EMBED + c4 * 4);
        *(float4*)&xs[row][c4 * 4] = vv;
        u16 h0 = f2bf(vv.x), h1 = f2bf(vv.y), h2 = f2bf(vv.z), h3 = f2bf(vv.w);
        ((ushort4*)x_hi)[(s0 + row) * 128 + c4] = make_ushort4(h0, h1, h2, h3);
    }
    #pragma unroll
    for (int i = 0; i < 16; ++i) {
        int idx = t + i * 256;
        ((float4*)wcs)[idx] = ((const float4*)WcT)[idx];
    }
    __syncthreads();
    int r = t >> 5, h2 = t & 31;
    const float* xr = xs[r];
    float acc = 0.f;
    #pragma unroll 8
    for (int k = 0; k < EMBED; ++k)
        acc += xr[k] * wcs[k * 32 + h2];
    int s = s0 + r;
    if (h2 < HID) A[(size_t)s * HID + h2] = acc + b1[h2];
    else          Bm[(size_t)s * HID + (h2 - 16)] = acc;
}

// ---------------- staging helpers (128B-row tiles, XOR swizzle; proven) ----------------
template<int NR>
__device__ __forceinline__ void stageR(const u16* src, int ld, int kt,
                                       u16* ldsb, int t)
{
    int kb0 = kt << 7;
    #pragma unroll
    for (int i = 0; i < NR / 32; ++i) {
        int row  = i * 32 + (t >> 3);
        int colb = (((t & 7) ^ ((t >> 3) & 7)) << 4);
        const char* g = (const char*)src + (size_t)row * ((size_t)ld * 2) + kb0 + colb;
        char* l = (char*)ldsb + i * 4096 + ((t >> 6) << 10) + ((t & 63) << 4);
        gload16(g, (char*)ldsb + i * 4096 + ((t >> 6) << 10) + ((t & 63) << 4));
        (void)l;
    }
}
__device__ __forceinline__ bf16x8 ldfrag(const u16* ldsb, int r, int s) {
    return *(const bf16x8*)((const char*)ldsb + r * 128 + (((s ^ (r & 7))) << 4));
}

// ---------------- Kernel 3: VT_hi[512][4096] = Wv(split) x X_hi^T ----------------
// 2-term: (wh+wl)*xh — x quantization error only. 64x64 tile, BK=64, dbuf.
__global__ __launch_bounds__(256, 2) void vgemm_kernel(
    const u16* __restrict__ Ah, const u16* __restrict__ Al,
    const u16* __restrict__ Bh, u16* __restrict__ outH)
{
    constexpr int TOFF = 64 * 64;
    __shared__ __attribute__((aligned(16))) u16 lds[2][3 * TOFF];   // 48 KB
    int t = threadIdx.x;
    int l = t & 63, wid = t >> 6;
    int wm = (wid >> 1) * 32, wn = (wid & 1) * 32;
    int m0 = blockIdx.y * 64, n0 = blockIdx.x * 64;
    const u16* pAh = Ah + (size_t)m0 * EMBED;
    const u16* pAl = Al + (size_t)m0 * EMBED;
    const u16* pBh = Bh + (size_t)n0 * EMBED;
    f32x4 acc[2][2] = {};

    auto STAGE = [&](int buf, int kt) {
        stageR<64>(pAh, EMBED, kt, lds[buf], t);
        stageR<64>(pAl, EMBED, kt, lds[buf] + TOFF, t);
        stageR<64>(pBh, EMBED, kt, lds[buf] + 2 * TOFF, t);
    };
    auto COMPUTE = [&](int buf) {
        #pragma unroll
        for (int kk = 0; kk < 2; ++kk) {
            int sb = (kk << 2) + (l >> 4);
            bf16x8 ah[2], al2[2], bh[2];
            #pragma unroll
            for (int mf = 0; mf < 2; ++mf) {
                int r = wm + mf * 16 + (l & 15);
                ah[mf]  = ldfrag(lds[buf], r, sb);
                al2[mf] = ldfrag(lds[buf] + TOFF, r, sb);
            }
            #pragma unroll
            for (int nf = 0; nf < 2; ++nf)
                bh[nf] = ldfrag(lds[buf] + 2 * TOFF, wn + nf * 16 + (l & 15), sb);
            #pragma unroll
            for (int mf = 0; mf < 2; ++mf)
                #pragma unroll
                for (int nf = 0; nf < 2; ++nf) {
                    acc[mf][nf] = __builtin_amdgcn_mfma_f32_16x16x32_bf16(ah[mf],  bh[nf], acc[mf][nf], 0, 0, 0);
                    acc[mf][nf] = __builtin_amdgcn_mfma_f32_16x16x32_bf16(al2[mf], bh[nf], acc[mf][nf], 0, 0, 0);
                }
        }
    };

    STAGE(0, 0);
    __syncthreads();
    int cur = 0;
    for (int kt = 0; kt + 1 < 8; ++kt) {
        STAGE(cur ^ 1, kt + 1);
        COMPUTE(cur);
        __syncthreads();
        cur ^= 1;
    }
    COMPUTE(cur);

    int cr = (l >> 4) << 2, cc = l & 15;
    #pragma unroll
    for (int mf = 0; mf < 2; ++mf)
        #pragma unroll
        for (int nf = 0; nf < 2; ++nf)
            #pragma unroll
            for (int r = 0; r < 4; ++r)
                outH[(size_t)(m0 + wm + mf * 16 + cr + r) * 4096
                     + n0 + wn + nf * 16 + cc] = f2bf(acc[mf][nf][r]);
}

// ---------------- Kernel 4: fused logits+softmax+PV ----------------
// Fixed-max softmax: s <= S0 = sum(|w|-w) strictly (tanh<1), so
// p~ = exp2((s-S0)*log2e) in (0,1]; out = (sum p~ V)/s_row at epilogue.
// 16 Q-rows/block, kv-chunks of 32, V(bf16) dbuf in LDS, P shared via LDS (hi+lo).
__global__ __launch_bounds__(256, 1) void fused_kernel(
    const float* __restrict__ A, const float* __restrict__ Bm,
    const float* __restrict__ w2, const u16* __restrict__ VT,
    float* __restrict__ out)
{
    __shared__ __attribute__((aligned(16))) u16 Vl[2][512 * 32];     // 2 x 32 KB
    __shared__ __attribute__((aligned(16))) float Bml[2][32 * 16];   // 2 x 2 KB
    __shared__ __attribute__((aligned(16))) u16 Pl[2][2][16 * 40];   // [par][hi/lo], 80B rows
    __shared__ float sred[4][16];
    __shared__ float srow[16];

    const float K2 = 2.8853900817779268f;   // 2*log2(e)
    const float L2E = 1.4426950408889634f;
    int t = threadIdx.x;
    int l = t & 63, w = t >> 6;
    int n = blockIdx.x;                      // 0..255
    int b = (n >> 1) & 3;                    // XCD-pair <-> batch affinity
    int m0 = ((((n & 1) << 5) | (n >> 3))) << 4;
    int prow = t & 15, pslot = t >> 4;

    // per-thread A-row constants (row m0+prow)
    const float4* Ar = (const float4*)(A + (size_t)(b * SEQ + m0 + prow) * HID);
    float4 a0 = Ar[0], a1 = Ar[1], a2 = Ar[2], a3 = Ar[3];
    float4 k0, k1, k2, k3;
    k0.x = K2*a0.x; k0.y = K2*a0.y; k0.z = K2*a0.z; k0.w = K2*a0.w;
    k1.x = K2*a1.x; k1.y = K2*a1.y; k1.z = K2*a1.z; k1.w = K2*a1.w;
    k2.x = K2*a2.x; k2.y = K2*a2.y; k2.z = K2*a2.z; k2.w = K2*a2.w;
    k3.x = K2*a3.x; k3.y = K2*a3.y; k3.z = K2*a3.z; k3.w = K2*a3.w;

    const float4* Wq4 = (const float4*)w2;
    float4 u0 = Wq4[0], u1 = Wq4[1], u2 = Wq4[2], u3 = Wq4[3];
    float Pa1 = -2.f*u0.x, Pa2 = -2.f*u0.y, Pas = Pa1 + Pa2;
    float Pb1 = -2.f*u0.z, Pb2 = -2.f*u0.w, Pbs = Pb1 + Pb2;
    float Pc1 = -2.f*u1.x, Pc2 = -2.f*u1.y, Pcs = Pc1 + Pc2;
    float Pd1 = -2.f*u1.z, Pd2 = -2.f*u1.w, Pds = Pd1 + Pd2;
    float Pe1 = -2.f*u2.x, Pe2 = -2.f*u2.y, Pes = Pe1 + Pe2;
    float Pf1 = -2.f*u2.z, Pf2 = -2.f*u2.w, Pfs = Pf1 + Pf2;
    float Pg1 = -2.f*u3.x, Pg2 = -2.f*u3.y, Pgs = Pg1 + Pg2;
    float Ph1 = -2.f*u3.z, Ph2 = -2.f*u3.w, Phs = Ph1 + Ph2;
    // S0 = sum max(-2w, 0) = sum(|w|-w) >= s always (strict since tanh<1)
    float S0 = fmaxf(Pa1,0.f)+fmaxf(Pa2,0.f)+fmaxf(Pb1,0.f)+fmaxf(Pb2,0.f)
             + fmaxf(Pc1,0.f)+fmaxf(Pc2,0.f)+fmaxf(Pd1,0.f)+fmaxf(Pd2,0.f)
             + fmaxf(Pe1,0.f)+fmaxf(Pe2,0.f)+fmaxf(Pf1,0.f)+fmaxf(Pf2,0.f)
             + fmaxf(Pg1,0.f)+fmaxf(Pg2,0.f)+fmaxf(Ph1,0.f)+fmaxf(Ph2,0.f);

    auto calc_lg = [&](float4 v0, float4 v1, float4 v2, float4 v3) -> float {
        float s = 0.f;
#define PAIRF(bx, by, kx, ky, P1, P2, PS) { \
        float e1 = __builtin_amdgcn_exp2f(fmaf(K2, (bx), (kx))); \
        float e2 = __builtin_amdgcn_exp2f(fmaf(K2, (by), (ky))); \
        float dd = fmaf(e1, e2, e1) + e2 + 1.0f; \
        float nn = fmaf((P1), e2, (PS)); nn = fmaf((P2), e1, nn); \
        s = fmaf(nn, __builtin_amdgcn_rcpf(dd), s); }
        PAIRF(v0.x, v0.y, k0.x, k0.y, Pa1, Pa2, Pas)
        PAIRF(v0.z, v0.w, k0.z, k0.w, Pb1, Pb2, Pbs)
        PAIRF(v1.x, v1.y, k1.x, k1.y, Pc1, Pc2, Pcs)
        PAIRF(v1.z, v1.w, k1.z, k1.w, Pd1, Pd2, Pds)
        PAIRF(v2.x, v2.y, k2.x, k2.y, Pe1, Pe2, Pes)
        PAIRF(v2.z, v2.w, k2.z, k2.w, Pf1, Pf2, Pfs)
        PAIRF(v3.x, v3.y, k3.x, k3.y, Pg1, Pg2, Pgs)
        PAIRF(v3.z, v3.w, k3.z, k3.w, Ph1, Ph2, Phs)
#undef PAIRF
        return s;
    };

    auto stageV = [&](int buf, int c) {
        size_t colbase = ((size_t)b << 10) + (c << 5);     // u16 col in VT
        #pragma unroll
        for (int i = 0; i < 8; ++i) {
            int row = (i << 6) + (t >> 2);
            int sl = ((t & 3) - (row >> 1)) & 3;           // logical slot at this phys slot
            const char* g = (const char*)(VT + (size_t)row * 4096 + colbase) + (sl << 4);
            gload16(g, (char*)&Vl[buf][0] + (i << 12) + (t << 4));
        }
    };
    auto stageB = [&](int buf, int c) {
        if (t < 128) {
            int row = t >> 2;                               // 0..31
            const char* g = (const char*)(Bm + ((size_t)(b << 10) + (c << 5) + row) * HID)
                          + ((t & 3) << 4);
            gload16(g, (char*)&Bml[buf][0] + (t << 4));
        }
    };

    f32x4 acc[8] = {};
    float s_part = 0.f;

    stageV(0, 0); stageB(0, 0);
    __syncthreads();

    #pragma unroll 1
    for (int c = 0; c < 32; ++c) {
        int pb = c & 1;
        if (c + 1 < 32) { stageV(pb ^ 1, c + 1); stageB(pb ^ 1, c + 1); }
        // two logits: kv = c*32 + pslot*2 + {0,1}
        const float4* br0 = (const float4*)&Bml[pb][(pslot * 2 + 0) * 16];
        const float4* br1 = (const float4*)&Bml[pb][(pslot * 2 + 1) * 16];
        float4 q0 = br0[0], q1 = br0[1], q2 = br0[2], q3 = br0[3];
        float4 r0 = br1[0], r1 = br1[1], r2 = br1[2], r3 = br1[3];
        float lg0 = calc_lg(q0, q1, q2, q3);
        float lg1 = calc_lg(r0, r1, r2, r3);
        float p0 = __builtin_amdgcn_exp2f((lg0 - S0) * L2E);
        float p1 = __builtin_amdgcn_exp2f((lg1 - S0) * L2E);
        s_part += p0 + p1;
        u16 h0 = f2bf(p0), lo0 = f2bf(p0 - bf2f(h0));
        u16 h1 = f2bf(p1), lo1 = f2bf(p1 - bf2f(h1));
        *(ushort2*)((char*)&Pl[pb][0][0] + prow * 80 + pslot * 4) = make_ushort2(h0, h1);
        *(ushort2*)((char*)&Pl[pb][1][0] + prow * 80 + pslot * 4) = make_ushort2(lo0, lo1);
        __syncthreads();                 // P visible; V(c)/Bm(c) drained at prev barrier
        bf16x8 pah = *(const bf16x8*)((const char*)&Pl[pb][0][0] + (l & 15) * 80 + ((l >> 4) << 4));
        bf16x8 pal = *(const bf16x8*)((const char*)&Pl[pb][1][0] + (l & 15) * 80 + ((l >> 4) << 4));
        #pragma unroll
        for (int nf = 0; nf < 8; ++nf) {
            int r = (w << 7) + (nf << 4) + (l & 15);
            int phys = ((l >> 4) + (r >> 1)) & 3;
            bf16x8 vb = *(const bf16x8*)((const char*)&Vl[pb][0] + r * 64 + (phys << 4));
            acc[nf] = __builtin_amdgcn_mfma_f32_16x16x32_bf16(pah, vb, acc[nf], 0, 0, 0);
            acc[nf] = __builtin_amdgcn_mfma_f32_16x16x32_bf16(pal, vb, acc[nf], 0, 0, 0);
        }
        __syncthreads();                 // protect Vl[pb]/Pl[pb] before next overwrite
    }

    // row-sum reduce: lanes share row = l&15 within wave; then cross-wave
    float sv = s_part;
    sv += __shfl_xor(sv, 16);
    sv += __shfl_xor(sv, 32);
    if (l < 16) sred[w][l] = sv;
    __syncthreads();
    if (t < 16) srow[t] = (sred[0][t] + sred[1][t]) + (sred[2][t] + sred[3][t]);
    __syncthreads();
    int rr = (l >> 4) << 2;
    float i0 = __fdividef(1.f, srow[rr + 0]);
    float i1 = __fdividef(1.f, srow[rr + 1]);
    float i2 = __fdividef(1.f, srow[rr + 2]);
    float i3 = __fdividef(1.f, srow[rr + 3]);
    #pragma unroll
    for (int nf = 0; nf < 8; ++nf) {
        size_t base = (size_t)(b * SEQ + m0 + rr) * EMBED + (w << 7) + (nf << 4) + (l & 15);
        out[base]             = acc[nf][0] * i0;
        out[base + EMBED]     = acc[nf][1] * i1;
        out[base + 2 * EMBED] = acc[nf][2] * i2;
        out[base + 3 * EMBED] = acc[nf][3] * i3;
    }
}

extern "C" void kernel_launch(void* const* d_in, const int* in_sizes, int n_in,
                              void* d_out, int out_size, void* d_ws, size_t ws_size,
                              hipStream_t stream) {
    const float* x   = (const float*)d_in[0];
    const float* Wq  = (const float*)d_in[1];
    const float* Wk  = (const float*)d_in[2];
    const float* Wvm = (const float*)d_in[3];
    const float* W1  = (const float*)d_in[4];
    const float* b1  = (const float*)d_in[5];
    const float* w2  = (const float*)d_in[6];
    // d_in[7] = b2: softmax shift-invariant, unused.

    char* ws = (char*)d_ws;
    float* WcT   = (float*)(ws + 0);          //    65,536 B
    float* A     = (float*)(ws + 65536);      //   262,144 B
    float* Bm    = (float*)(ws + 327680);     //   262,144 B
    u16*   VT_hi = (u16*)(ws + 589824);       // 4,194,304 B  [512][4096]
    u16*   x_hi  = (u16*)(ws + 4784128);      // 4,194,304 B  [4096][512]
    u16*   wv_hi = (u16*)(ws + 8978432);      //   524,288 B
    u16*   wv_lo = (u16*)(ws + 9502720);      //   524,288 B
    float* out   = (float*)d_out;

    hipLaunchKernelGGL(wc_kernel, dim3(288), dim3(256), 0, stream,
                       Wq, Wk, W1, Wvm, WcT, wv_hi, wv_lo);
    hipLaunchKernelGGL(ab_kernel, dim3(512), dim3(256), 0, stream,
                       x, WcT, b1, A, Bm, x_hi);
    hipLaunchKernelGGL(vgemm_kernel, dim3(64, 8), dim3(256), 0, stream,
                       wv_hi, wv_lo, x_hi, VT_hi);
    hipLaunchKernelGGL(fused_kernel, dim3(256), dim3(256), 0, stream,
                       A, Bm, w2, VT_hi, out);
}